// Round 4
// baseline (8341.744 us; speedup 1.0000x reference)
//
#include <hip/hip_runtime.h>

typedef _Float16 h2f __attribute__((ext_vector_type(2)));
typedef _Float16 f16x8 __attribute__((ext_vector_type(8)));
typedef float f32x4 __attribute__((ext_vector_type(4)));
typedef unsigned int u32;
typedef unsigned short u16;

#define B_ 128
#define S_ 1024
#define I_ 256
#define H_ 512
#define O_ 256
#define IH_ 768

__device__ __forceinline__ u32 pack2(float x, float y) {
    return __builtin_bit_cast(u32, __builtin_amdgcn_cvt_pkrtz(x, y));
}
__device__ __forceinline__ u16 f2h(float x) { return __builtin_bit_cast(u16, (_Float16)x); }
__device__ __forceinline__ float h2f_(u16 x) { return (float)__builtin_bit_cast(_Float16, x); }

__device__ __forceinline__ float tanh_fast(float x) {
    float e = __expf(-2.f * fabsf(x));     // e in (0,1] -- no overflow path
    float r = (1.f - e) / (1.f + e);
    return copysignf(r, x);
}

// MFMA helpers: D = A(16x32) * B(32x16) + C, f16 in / f32 acc.
// Verified layouts (m89/m91/m120): A[m=lane&15][k=(lane>>4)*8+j],
// B[k=(lane>>4)*8+j][n=lane&15], C/D col=lane&15 row=(lane>>4)*4+reg.
__device__ __forceinline__ f32x4 mfx(uint4 a, uint4 b, f32x4 c) {
    return __builtin_amdgcn_mfma_f32_16x16x32_f16(
        __builtin_bit_cast(f16x8, a), __builtin_bit_cast(f16x8, b), c, 0, 0, 0);
}
__device__ __forceinline__ f32x4 mf(uint4 a, const uint4* bp, f32x4 c) {
    uint4 b = *bp;
    return mfx(a, b, c);
}

#define REP8(X)  X(0) X(1) X(2) X(3) X(4) X(5) X(6) X(7)
#define REP16(X) REP8(X) X(8) X(9) X(10) X(11) X(12) X(13) X(14) X(15)

// ---------------------------------------------------------------------------
// Workspace layout (bytes):
//   wxb4 @ 0        : 16384 uint4 (256 KB)  Wx octets  [q 0..31][col 0..511]
//                     octet q of col c = W[c][q*8 .. q*8+7] as f16
//   whb4 @ 256 KB   : 32768 uint4 (512 KB)  Wh octets  [q 0..63][n 0..511]
//                     octet q of col n = W[n][256+q*8 .. +7] as f16
//   hx   @ 768 KB   : 2 bufs x 8 grp x 8 slc x (16 x 64) f16  (256 KB)
//   cnt  @ 1 MB     : 8 ints (group arrival counters)
//   pre  @ 1.0625 MB: 128*1024*512 f16 (128 MB)
// ---------------------------------------------------------------------------
#define WXB_OFF 0
#define WHB_OFF (256u << 10)
#define HX_OFF  (768u << 10)
#define CNT_OFF (1u << 20)
#define PRE_OFF 0x110000u

__global__ __launch_bounds__(256) void k_convert(const float* __restrict__ W,
                                                 uint4* __restrict__ wxb4,
                                                 uint4* __restrict__ whb4,
                                                 int* __restrict__ cnt) {
    if (blockIdx.x == 0 && threadIdx.x < 8) cnt[threadIdx.x] = 0;
    int idx = blockIdx.x * 256 + threadIdx.x;       // 0..49151
    if (idx < 16384) {                               // wxb: q = idx>>9 (0..31)
        int q = idx >> 9, col = idx & 511;
        const float4* r = (const float4*)(W + (long)col * IH_ + q * 8);
        float4 u = r[0], v = r[1];
        wxb4[idx] = (uint4){pack2(u.x, u.y), pack2(u.z, u.w),
                            pack2(v.x, v.y), pack2(v.z, v.w)};
    } else {                                         // whb: q = 0..63
        int i2 = idx - 16384;
        int q = i2 >> 9, n = i2 & 511;
        const float4* r = (const float4*)(W + (long)n * IH_ + I_ + q * 8);
        float4 u = r[0], v = r[1];
        whb4[i2] = (uint4){pack2(u.x, u.y), pack2(u.z, u.w),
                           pack2(v.x, v.y), pack2(v.z, v.w)};
    }
}

// ---------------------------------------------------------------------------
// Phase 1 (MFMA GEMM): pre[r][j] = b_i2h[j] + sum_i x[r][i]*Wx[i][j], f16 out.
// Grid 2048 WGs x 256 thr; WG = 64 seq-rows (4 waves x 16), N=512 in 2 halves.
// A-frags (8) built once from seq fp32 -> f16; B streamed from L2 (Wx hot).
// waves_per_eu(2,2): pin RA budget to 256 VGPR -- no occupancy-chasing spills.
// ---------------------------------------------------------------------------
__global__ __launch_bounds__(256) __attribute__((amdgpu_waves_per_eu(2, 2)))
void k_phase1(const float* __restrict__ seq, const uint4* __restrict__ wxb4,
              const float* __restrict__ bias, u16* __restrict__ pre) {
    int w = threadIdx.x >> 6, l = threadIdx.x & 63;
    int lm = l & 15, lq = l >> 4;
    int mb_w = blockIdx.x * 64 + w * 16;
    long xrow = (long)(mb_w + lm) * I_;
#define DECLA1(k) uint4 a##k; { \
        const float4* xp = (const float4*)(seq + xrow + (k)*32 + lq*8); \
        float4 u = xp[0], v = xp[1]; \
        a##k = (uint4){pack2(u.x,u.y), pack2(u.z,u.w), pack2(v.x,v.y), pack2(v.z,v.w)}; }
    REP8(DECLA1)
#undef DECLA1
    int mrow0 = mb_w + lq * 4;
#pragma unroll
    for (int half = 0; half < 2; ++half) {
        int colbase = half * 256;
        const uint4* bptr = wxb4 + colbase + lm;
#define DECLC(n) float bv##n = bias[colbase + (n)*16 + lm]; \
                 f32x4 c##n = {bv##n, bv##n, bv##n, bv##n};
        REP16(DECLC)
#undef DECLC
#define ROW(k,n) c##n = mf(a##k, bptr + ((k)*4 + lq)*512 + (n)*16, c##n);
#define KS(k) ROW(k,0) ROW(k,1) ROW(k,2) ROW(k,3) ROW(k,4) ROW(k,5) ROW(k,6) ROW(k,7) \
              ROW(k,8) ROW(k,9) ROW(k,10) ROW(k,11) ROW(k,12) ROW(k,13) ROW(k,14) ROW(k,15)
        KS(0) KS(1) KS(2) KS(3) KS(4) KS(5) KS(6) KS(7)
#undef KS
#undef ROW
#define STN(n) { long cb = (long)colbase + (n)*16 + lm; \
        pre[(long)(mrow0+0)*H_ + cb] = f2h(c##n[0]); \
        pre[(long)(mrow0+1)*H_ + cb] = f2h(c##n[1]); \
        pre[(long)(mrow0+2)*H_ + cb] = f2h(c##n[2]); \
        pre[(long)(mrow0+3)*H_ + cb] = f2h(c##n[3]); }
        REP16(STN)
#undef STN
    }
}

// ---------------------------------------------------------------------------
// Phase 2: MFMA recurrence with cross-WG column-slice exchange.
// 64 WGs = 8 batch-groups (16 rows) x 8 col-slices (64 cols); g = blockIdx&7
// so a group's 8 slices land on one XCD under the %8 round-robin heuristic
// (perf-only; correctness from agent-scope fences/atomics either way).
// Per wave: 1 N-tile (16 cols), B = 16 resident uint4 (64 VGPR, budget 512
// via waves_per_eu(1,1)), per step: 16 A-loads from partner slices (L2),
// 16 MFMA as two 8-chains, tanh, publish slice, bump group counter.
// Double-buffered hx: writer of h_t (buf t&1) waited for all h_{t-1}
// publishes, which implies partners finished reading buf t&1's old data.
// ---------------------------------------------------------------------------
__global__ __launch_bounds__(256) __attribute__((amdgpu_waves_per_eu(1, 1)))
void k_phase2(const u16* __restrict__ pre, const uint4* __restrict__ whb4,
              u16* __restrict__ hx, int* __restrict__ cnt,
              const float* __restrict__ Who, const float* __restrict__ bo,
              float* __restrict__ out) {
    int g = blockIdx.x & 7, s = blockIdx.x >> 3;
    int tid = threadIdx.x, w = tid >> 6, l = tid & 63;
    int lm = l & 15, lq = l >> 4;
    int n_loc = w * 16 + lm;
    int n_glob = s * 64 + n_loc;
    int slice = g * 8 + s;
    const uint4* wb = whb4 + n_glob;
#define DECLB(i) uint4 b##i = wb[((i)*4 + lq) * 512];
    REP16(DECLB)
#undef DECLB
    int m0 = lq * 4;                                 // C/D rows m0..m0+3
    const u16* pr0 = pre + (long)(g*16 + m0 + 0) * S_ * H_ + n_glob;
    const u16* pr1 = pre + (long)(g*16 + m0 + 1) * S_ * H_ + n_glob;
    const u16* pr2 = pre + (long)(g*16 + m0 + 2) * S_ * H_ + n_glob;
    const u16* pr3 = pre + (long)(g*16 + m0 + 3) * S_ * H_ + n_glob;
    u16* my0 = hx + slice * 1024;                    // buf0 slice (16x64 f16)
    u16* my1 = hx + (64 + slice) * 1024;             // buf1 slice

    // t = 0: h0 = tanh(pre0), no matmul, no wait.
    my0[(m0+0)*64 + n_loc] = f2h(tanh_fast(h2f_(pr0[0])));
    my0[(m0+1)*64 + n_loc] = f2h(tanh_fast(h2f_(pr1[0])));
    my0[(m0+2)*64 + n_loc] = f2h(tanh_fast(h2f_(pr2[0])));
    my0[(m0+3)*64 + n_loc] = f2h(tanh_fast(h2f_(pr3[0])));
    u16 p0 = pr0[512], p1 = pr1[512], p2 = pr2[512], p3 = pr3[512]; // pre(1)
    __syncthreads();                                  // drains stores (vmcnt 0)
    if (tid == 0) { __threadfence(); atomicAdd(cnt + g, 1); }

    for (int t = 1; t < S_; ++t) {
        if (tid == 0) {
            int need = t * 8;
            while (__hip_atomic_load(cnt + g, __ATOMIC_RELAXED,
                                     __HIP_MEMORY_SCOPE_AGENT) < need) {}
        }
        __syncthreads();
        __threadfence();                              // invalidate stale L1/L2
        const u16* hp = hx + (((t-1) & 1) * 64 + g * 8) * 1024 + lm * 64 + lq * 8;
#define DECLA(i) uint4 a##i = *(const uint4*)(hp + ((i) >> 1) * 1024 + ((i) & 1) * 32);
        REP16(DECLA)
#undef DECLA
        long tnoff = (t < S_ - 1) ? (long)(t + 1) * H_ : (long)t * H_;
        u16 np0 = pr0[tnoff], np1 = pr1[tnoff], np2 = pr2[tnoff], np3 = pr3[tnoff];
        f32x4 acc0 = { h2f_(p0), h2f_(p1), h2f_(p2), h2f_(p3) };
        f32x4 acc1 = { 0.f, 0.f, 0.f, 0.f };
#define MMI(i,j) acc0 = mfx(a##i, b##i, acc0); acc1 = mfx(a##j, b##j, acc1);
        MMI(0,8) MMI(1,9) MMI(2,10) MMI(3,11) MMI(4,12) MMI(5,13) MMI(6,14) MMI(7,15)
#undef MMI
        f32x4 av = acc0 + acc1;
        u16* my = (t & 1) ? my1 : my0;
        my[(m0+0)*64 + n_loc] = f2h(tanh_fast(av[0]));
        my[(m0+1)*64 + n_loc] = f2h(tanh_fast(av[1]));
        my[(m0+2)*64 + n_loc] = f2h(tanh_fast(av[2]));
        my[(m0+3)*64 + n_loc] = f2h(tanh_fast(av[3]));
        p0 = np0; p1 = np1; p2 = np2; p3 = np3;
        __syncthreads();
        if (tid == 0) { __threadfence(); atomicAdd(cnt + g, 1); }
    }

    // Epilogue: wait for everyone's h_1023 (buf1), then outputs.
    if (tid == 0) {
        while (__hip_atomic_load(cnt + g, __ATOMIC_RELAXED,
                                 __HIP_MEMORY_SCOPE_AGENT) < 8 * S_) {}
    }
    __syncthreads();
    __threadfence();
    const u16* hf = hx + (64 + g * 8) * 1024;        // buf1, group base
    {   // hidden out: own slice, 4 contiguous cols per thread
        int m = tid >> 4, c4 = (tid & 15) * 4;
        const u16* pv = hf + s * 1024 + m * 64 + c4;
        float4 hv = { h2f_(pv[0]), h2f_(pv[1]), h2f_(pv[2]), h2f_(pv[3]) };
        *(float4*)(out + (long)B_ * O_ + (long)(g*16 + m) * H_ + s * 64 + c4) = hv;
    }
    {   // output proj: o in [s*32, s*32+32), 2 batch rows per thread
        int o = s * 32 + (tid & 31);
        const float* wr = Who + (long)o * H_;
        float bov = bo[o];
        for (int mi = tid >> 5; mi < 16; mi += 8) {
            float acc = bov;
            for (int q = 0; q < 64; ++q) {           // k-octet q: k = q*8
                const u16* hq = hf + (q >> 3) * 1024 + mi * 64 + (q & 7) * 8;
#pragma unroll
                for (int jj = 0; jj < 8; ++jj)
                    acc += h2f_(hq[jj]) * wr[q * 8 + jj];
            }
            out[(long)(g*16 + mi) * O_ + o] = acc;
        }
    }
}

// ---------------------------------------------------------------------------
// Fallback (workspace too small): straightforward fp32, correct but slow.
// ---------------------------------------------------------------------------
__global__ __launch_bounds__(512) void k_fallback(const float* __restrict__ seq,
                                                  const float* __restrict__ W,
                                                  const float* __restrict__ bias,
                                                  const float* __restrict__ Who,
                                                  const float* __restrict__ bo,
                                                  float* __restrict__ out) {
    __shared__ float hb[2][H_];
    int b = blockIdx.x, j = threadIdx.x;
    const float* wrow = W + (long)j * IH_;
    float bj = bias[j];
    hb[0][j] = 0.f;
    __syncthreads();
    for (int t = 0; t < S_; ++t) {
        const float* x = seq + ((long)b * S_ + t) * I_;
        float acc = bj;
        for (int i = 0; i < I_; ++i) acc += x[i] * wrow[i];
        const float* hc = hb[t & 1];
        for (int k = 0; k < H_; ++k) acc += hc[k] * wrow[I_ + k];
        hb[(t & 1) ^ 1][j] = tanh_fast(acc);
        __syncthreads();
    }
    float hj = hb[0][j];
    out[(long)B_ * O_ + (long)b * H_ + j] = hj;
    if (j < O_) {
        float acc = bo[j];
        const float* wr = Who + (long)j * H_;
        for (int k = 0; k < H_; ++k) acc += hb[0][k] * wr[k];
        out[(long)b * O_ + j] = acc;
    }
}

extern "C" void kernel_launch(void* const* d_in, const int* in_sizes, int n_in,
                              void* d_out, int out_size, void* d_ws, size_t ws_size,
                              hipStream_t stream) {
    const float* seq = (const float*)d_in[0];   // (128,1024,256) fp32
    const float* W   = (const float*)d_in[1];   // (512,768) fp32
    const float* bi  = (const float*)d_in[2];   // (512,)
    const float* Who = (const float*)d_in[3];   // (256,512)
    const float* bo  = (const float*)d_in[4];   // (256,)
    float* out = (float*)d_out;                 // 32768 output + 65536 hidden

    const size_t WS_NEED = (size_t)PRE_OFF + (size_t)B_ * S_ * H_ * 2;

    if (ws_size >= WS_NEED) {
        char* ws = (char*)d_ws;
        uint4* wxb4 = (uint4*)(ws + WXB_OFF);
        uint4* whb4 = (uint4*)(ws + WHB_OFF);
        u16*   hx   = (u16*)(ws + HX_OFF);
        int*   cnt  = (int*)(ws + CNT_OFF);
        u16*   pre  = (u16*)(ws + PRE_OFF);
        k_convert<<<192, 256, 0, stream>>>(W, wxb4, whb4, cnt);
        k_phase1<<<2048, 256, 0, stream>>>(seq, wxb4, bi, pre);
        k_phase2<<<64, 256, 0, stream>>>(pre, whb4, hx, cnt, Who, bo, out);
    } else {
        k_fallback<<<B_, 512, 0, stream>>>(seq, W, bi, Who, bo, out);
    }
}

// Round 5
// 2845.047 us; speedup vs baseline: 2.9320x; 2.9320x over previous
//
#include <hip/hip_runtime.h>

typedef _Float16 h2f __attribute__((ext_vector_type(2)));
typedef _Float16 f16x8 __attribute__((ext_vector_type(8)));
typedef float f32x4 __attribute__((ext_vector_type(4)));
typedef unsigned int u32;
typedef unsigned short u16;

#define B_ 128
#define S_ 1024
#define I_ 256
#define H_ 512
#define O_ 256
#define IH_ 768

#if __has_builtin(__builtin_amdgcn_fdot2)
__device__ __forceinline__ float fdot2u(u32 a, u32 b, float c) {
    return __builtin_amdgcn_fdot2(__builtin_bit_cast(h2f, a),
                                  __builtin_bit_cast(h2f, b), c, false);
}
#else
__device__ __forceinline__ float fdot2u(u32 a, u32 b, float c) {
    h2f av = __builtin_bit_cast(h2f, a), bv = __builtin_bit_cast(h2f, b);
    return c + (float)av.x * (float)bv.x + (float)av.y * (float)bv.y;
}
#endif

__device__ __forceinline__ u32 pack2(float x, float y) {
    return __builtin_bit_cast(u32, __builtin_amdgcn_cvt_pkrtz(x, y));
}
__device__ __forceinline__ u16 f2h(float x) { return __builtin_bit_cast(u16, (_Float16)x); }
__device__ __forceinline__ float h2f_(u16 x) { return (float)__builtin_bit_cast(_Float16, x); }

__device__ __forceinline__ float tanh_fast(float x) {
    float e = __expf(-2.f * fabsf(x));     // e in (0,1] -- no overflow path
    float r = (1.f - e) / (1.f + e);
    return copysignf(r, x);
}

// MFMA helper (phase 1): D = A(16x32)*B(32x16)+C, f16 in / f32 acc.
// Verified layouts (m89/m91): A[m=lane&15][k=(lane>>4)*8+j],
// B[k=(lane>>4)*8+j][n=lane&15], C/D col=lane&15 row=(lane>>4)*4+reg.
__device__ __forceinline__ f32x4 mfx(uint4 a, uint4 b, f32x4 c) {
    return __builtin_amdgcn_mfma_f32_16x16x32_f16(
        __builtin_bit_cast(f16x8, a), __builtin_bit_cast(f16x8, b), c, 0, 0, 0);
}
__device__ __forceinline__ f32x4 mf(uint4 a, const uint4* bp, f32x4 c) {
    uint4 b = *bp;
    return mfx(a, b, c);
}

#define REP8(X)  X(0) X(1) X(2) X(3) X(4) X(5) X(6) X(7)
#define REP16(X) REP8(X) X(8) X(9) X(10) X(11) X(12) X(13) X(14) X(15)
// resident-weight repetition, split for scheduling (21 + 21 = 42)
#define REPW_A(X) X(0) X(1) X(2) X(3) X(4) X(5) X(6) X(7) X(8) X(9) X(10) \
                  X(11) X(12) X(13) X(14) X(15) X(16) X(17) X(18) X(19) X(20)
#define REPW_B(X) X(21) X(22) X(23) X(24) X(25) X(26) X(27) X(28) X(29) X(30) \
                  X(31) X(32) X(33) X(34) X(35) X(36) X(37) X(38) X(39) X(40) X(41)
#define REP42(X) REPW_A(X) REPW_B(X)
#define REPS_A(X) X(0) X(1) X(2) X(3) X(4) X(5) X(6) X(7)
#define REPS_B(X) X(8) X(9) X(10) X(11) X(12) X(13) X(14) X(15)
#define REPT(X) X(0) X(1) X(2) X(3) X(4) X(5)

// ---------------------------------------------------------------------------
// Workspace layout (bytes):
//   wxb4 @ 0      : 16384 uint4 (256 KB)  Wx octets [q 0..31][col 0..511]
//                   octet q of col c = W[c][q*8 .. q*8+7] as f16
//   whb4 @ 256 KB : 32768 uint4 (512 KB)  Wh octets [q 0..63][n 0..511]
//                   octet q of col n = W[n][256+q*8 .. +7] as f16
//                   (= pair-dwords 4q..4q+3 of col n -- phase2's slab layout)
//   pre  @ 1 MB   : 128*1024*512 f16 (128 MB)
// ---------------------------------------------------------------------------
#define WXB_OFF 0
#define WHB_OFF (256u << 10)
#define PRE_OFF (1u << 20)

__global__ __launch_bounds__(256) void k_convert(const float* __restrict__ W,
                                                 uint4* __restrict__ wxb4,
                                                 uint4* __restrict__ whb4) {
    int idx = blockIdx.x * 256 + threadIdx.x;       // 0..49151
    if (idx < 16384) {                               // wxb: q = idx>>9 (0..31)
        int q = idx >> 9, col = idx & 511;
        const float4* r = (const float4*)(W + (long)col * IH_ + q * 8);
        float4 u = r[0], v = r[1];
        wxb4[idx] = (uint4){pack2(u.x, u.y), pack2(u.z, u.w),
                            pack2(v.x, v.y), pack2(v.z, v.w)};
    } else {                                         // whb: q = 0..63
        int i2 = idx - 16384;
        int q = i2 >> 9, n = i2 & 511;
        const float4* r = (const float4*)(W + (long)n * IH_ + I_ + q * 8);
        float4 u = r[0], v = r[1];
        whb4[i2] = (uint4){pack2(u.x, u.y), pack2(u.z, u.w),
                           pack2(v.x, v.y), pack2(v.z, v.w)};
    }
}

// ---------------------------------------------------------------------------
// Phase 1 (MFMA GEMM, measured ~40 us in R4 -- unchanged):
// pre[r][j] = b_i2h[j] + sum_i x[r][i]*Wx[i][j], f16 out.
// Grid 2048 WGs x 256 thr; WG = 64 seq-rows (4 waves x 16), N=512 in 2 halves.
// ---------------------------------------------------------------------------
__global__ __launch_bounds__(256) __attribute__((amdgpu_waves_per_eu(2, 2)))
void k_phase1(const float* __restrict__ seq, const uint4* __restrict__ wxb4,
              const float* __restrict__ bias, u16* __restrict__ pre) {
    int w = threadIdx.x >> 6, l = threadIdx.x & 63;
    int lm = l & 15, lq = l >> 4;
    int mb_w = blockIdx.x * 64 + w * 16;
    long xrow = (long)(mb_w + lm) * I_;
#define DECLA1(k) uint4 a##k; { \
        const float4* xp = (const float4*)(seq + xrow + (k)*32 + lq*8); \
        float4 u = xp[0], v = xp[1]; \
        a##k = (uint4){pack2(u.x,u.y), pack2(u.z,u.w), pack2(v.x,v.y), pack2(v.z,v.w)}; }
    REP8(DECLA1)
#undef DECLA1
    int mrow0 = mb_w + lq * 4;
#pragma unroll
    for (int half = 0; half < 2; ++half) {
        int colbase = half * 256;
        const uint4* bptr = wxb4 + colbase + lm;
#define DECLC(n) float bv##n = bias[colbase + (n)*16 + lm]; \
                 f32x4 c##n = {bv##n, bv##n, bv##n, bv##n};
        REP16(DECLC)
#undef DECLC
#define ROW(k,n) c##n = mf(a##k, bptr + ((k)*4 + lq)*512 + (n)*16, c##n);
#define KS(k) ROW(k,0) ROW(k,1) ROW(k,2) ROW(k,3) ROW(k,4) ROW(k,5) ROW(k,6) ROW(k,7) \
              ROW(k,8) ROW(k,9) ROW(k,10) ROW(k,11) ROW(k,12) ROW(k,13) ROW(k,14) ROW(k,15)
        KS(0) KS(1) KS(2) KS(3) KS(4) KS(5) KS(6) KS(7)
#undef KS
#undef ROW
#define STN(n) { long cb = (long)colbase + (n)*16 + lm; \
        pre[(long)(mrow0+0)*H_ + cb] = f2h(c##n[0]); \
        pre[(long)(mrow0+1)*H_ + cb] = f2h(c##n[1]); \
        pre[(long)(mrow0+2)*H_ + cb] = f2h(c##n[2]); \
        pre[(long)(mrow0+3)*H_ + cb] = f2h(c##n[3]); }
        REP16(STN)
#undef STN
    }
}

// ---------------------------------------------------------------------------
// Phase 2: persistent dot2 recurrence, one WG per batch row (128 WGs x 512).
// Thread j owns hidden column j = 64 uint4 weight slabs (whb4[q][j]):
//   q  0..41 : 42 NAMED uint4 in VGPRs (168 regs; amdgpu_waves_per_eu(2,2)
//              pins the RA budget to 256 -- the R1/R3 spill fix)
//   q 42..47 : 6 slabs LDS-resident (48 KB static, filled once)
//   q 48..63 : 16 slabs streamed from L2 per step, two 8-chunks
// h ping-pong in LDS f16; lane l reads h pairs 4l..4l+3 (one ds_read_b128),
// pair 4q+c broadcast from lane q via v_readlane. One barrier per step.
// zoff/lz asm-barriers block LICM (hoisting 64 uint4 = the spill trigger).
// ---------------------------------------------------------------------------
__global__ __launch_bounds__(512) __attribute__((amdgpu_waves_per_eu(2, 2)))
void k_phase2(const u16* __restrict__ pre, const uint4* __restrict__ whb4,
              const float* __restrict__ Who, const float* __restrict__ bo,
              float* __restrict__ out) {
    __shared__ __align__(16) uint4 wlds[6 * 512];   // 48 KB, slabs q=42..47
    __shared__ __align__(16) u16 hbuf[2][H_];
    int b = blockIdx.x, j = threadIdx.x, lane = j & 63;
#define DECLW(i) uint4 w##i = whb4[(i) * 512 + j];
    REP42(DECLW)
#undef DECLW
#pragma unroll
    for (int s_ = 0; s_ < 6; ++s_) wlds[s_ * 512 + j] = whb4[(42 + s_) * 512 + j];
    const u16* prow = pre + (long)b * S_ * H_ + j;
    hbuf[0][j] = 0;                                 // h_{-1} = 0
    __syncthreads();
    u16 pv = prow[0];                               // pre for t=0
    for (int t = 0; t < S_; ++t) {
        int cur = t & 1, nxt = cur ^ 1;
        long tn = (t + 1 < S_) ? (long)(t + 1) : (long)t;
        int zoff = 0, lz = 0;
        asm volatile("" : "+v"(zoff), "+v"(lz));    // block LICM of weight loads
        u16 pnext = prow[tn * H_];                  // prefetch next step's pre
        uint4 hv = ((const uint4*)hbuf[cur])[lane]; // lane l: h pairs 4l..4l+3
        float a0 = h2f_(pv), a1 = 0.f, a2 = 0.f, a3 = 0.f;
#define SLOAD(i) uint4 s##i = whb4[(48 + (i)) * 512 + j + zoff];
#define SDOT(i) \
        a0 = fdot2u((u32)__builtin_amdgcn_readlane((int)hv.x, 48 + (i)), s##i.x, a0); \
        a1 = fdot2u((u32)__builtin_amdgcn_readlane((int)hv.y, 48 + (i)), s##i.y, a1); \
        a2 = fdot2u((u32)__builtin_amdgcn_readlane((int)hv.z, 48 + (i)), s##i.z, a2); \
        a3 = fdot2u((u32)__builtin_amdgcn_readlane((int)hv.w, 48 + (i)), s##i.w, a3);
#define DOTR(i) \
        a0 = fdot2u((u32)__builtin_amdgcn_readlane((int)hv.x, (i)), w##i.x, a0); \
        a1 = fdot2u((u32)__builtin_amdgcn_readlane((int)hv.y, (i)), w##i.y, a1); \
        a2 = fdot2u((u32)__builtin_amdgcn_readlane((int)hv.z, (i)), w##i.z, a2); \
        a3 = fdot2u((u32)__builtin_amdgcn_readlane((int)hv.w, (i)), w##i.w, a3);
#define LLOAD(i) uint4 t##i = wlds[(i) * 512 + j + lz];
#define LDOT(i) \
        a0 = fdot2u((u32)__builtin_amdgcn_readlane((int)hv.x, 42 + (i)), t##i.x, a0); \
        a1 = fdot2u((u32)__builtin_amdgcn_readlane((int)hv.y, 42 + (i)), t##i.y, a1); \
        a2 = fdot2u((u32)__builtin_amdgcn_readlane((int)hv.z, 42 + (i)), t##i.z, a2); \
        a3 = fdot2u((u32)__builtin_amdgcn_readlane((int)hv.w, 42 + (i)), t##i.w, a3);
        REPS_A(SLOAD)                               // chunk A in flight (8)
        REPW_A(DOTR)                                // 21 resident slabs
        REPS_A(SDOT)
        __builtin_amdgcn_sched_barrier(0);          // keep chunk B below chunk A
        REPS_B(SLOAD)                               // chunk B in flight (8)
        REPT(LLOAD)                                 // 6 LDS slabs in flight
        REPW_B(DOTR)                                // 21 resident slabs
        REPS_B(SDOT)
        REPT(LDOT)
#undef SLOAD
#undef SDOT
#undef DOTR
#undef LLOAD
#undef LDOT
        float acc = (a0 + a1) + (a2 + a3);
        float r = tanh_fast(acc);
        hbuf[nxt][j] = f2h(r);
        pv = pnext;
        __syncthreads();
    }
    // final h lives in hbuf[0] (last write: t=1023 -> nxt=0)
    float hj = h2f_(hbuf[0][j]);
    out[(long)B_ * O_ + (long)b * H_ + j] = hj;     // hidden output
    if (j < O_) {                                   // o = h @ W_h2o^T + b_h2o
        float acc = bo[j];
        const float4* wr = (const float4*)(Who + (long)j * H_);
        const u16* hb = hbuf[0];
#pragma unroll 4
        for (int k = 0; k < 128; ++k) {
            float4 wv = wr[k];
            acc += h2f_(hb[4 * k + 0]) * wv.x
                 + h2f_(hb[4 * k + 1]) * wv.y
                 + h2f_(hb[4 * k + 2]) * wv.z
                 + h2f_(hb[4 * k + 3]) * wv.w;
        }
        out[(long)b * O_ + j] = acc;
    }
}

// ---------------------------------------------------------------------------
// Fallback (workspace too small): straightforward fp32, correct but slow.
// ---------------------------------------------------------------------------
__global__ __launch_bounds__(512) void k_fallback(const float* __restrict__ seq,
                                                  const float* __restrict__ W,
                                                  const float* __restrict__ bias,
                                                  const float* __restrict__ Who,
                                                  const float* __restrict__ bo,
                                                  float* __restrict__ out) {
    __shared__ float hb[2][H_];
    int b = blockIdx.x, j = threadIdx.x;
    const float* wrow = W + (long)j * IH_;
    float bj = bias[j];
    hb[0][j] = 0.f;
    __syncthreads();
    for (int t = 0; t < S_; ++t) {
        const float* x = seq + ((long)b * S_ + t) * I_;
        float acc = bj;
        for (int i = 0; i < I_; ++i) acc += x[i] * wrow[i];
        const float* hc = hb[t & 1];
        for (int k = 0; k < H_; ++k) acc += hc[k] * wrow[I_ + k];
        hb[(t & 1) ^ 1][j] = tanh_fast(acc);
        __syncthreads();
    }
    float hj = hb[0][j];
    out[(long)B_ * O_ + (long)b * H_ + j] = hj;
    if (j < O_) {
        float acc = bo[j];
        const float* wr = Who + (long)j * H_;
        for (int k = 0; k < H_; ++k) acc += hb[0][k] * wr[k];
        out[(long)b * O_ + j] = acc;
    }
}

extern "C" void kernel_launch(void* const* d_in, const int* in_sizes, int n_in,
                              void* d_out, int out_size, void* d_ws, size_t ws_size,
                              hipStream_t stream) {
    const float* seq = (const float*)d_in[0];   // (128,1024,256) fp32
    const float* W   = (const float*)d_in[1];   // (512,768) fp32
    const float* bi  = (const float*)d_in[2];   // (512,)
    const float* Who = (const float*)d_in[3];   // (256,512)
    const float* bo  = (const float*)d_in[4];   // (256,)
    float* out = (float*)d_out;                 // 32768 output + 65536 hidden

    const size_t WS_NEED = (size_t)PRE_OFF + (size_t)B_ * S_ * H_ * 2;

    if (ws_size >= WS_NEED) {
        char* ws = (char*)d_ws;
        uint4* wxb4 = (uint4*)(ws + WXB_OFF);
        uint4* whb4 = (uint4*)(ws + WHB_OFF);
        u16*   pre  = (u16*)(ws + PRE_OFF);
        k_convert<<<192, 256, 0, stream>>>(W, wxb4, whb4);
        k_phase1<<<2048, 256, 0, stream>>>(seq, wxb4, bi, pre);
        k_phase2<<<B_, 512, 0, stream>>>(pre, whb4, Who, bo, out);
    } else {
        k_fallback<<<B_, 512, 0, stream>>>(seq, W, bi, Who, bo, out);
    }
}